// Round 12
// baseline (499.686 us; speedup 1.0000x reference)
//
#include <hip/hip_runtime.h>

typedef __attribute__((ext_vector_type(8))) short bfrag;   // 8 bf16 (4 VGPRs)
typedef __attribute__((ext_vector_type(4))) float ffrag;   // 4 fp32

__device__ __forceinline__ unsigned short f2b(float f){
  unsigned int u = __float_as_uint(f);
  return (unsigned short)((u + 0x7FFFu + ((u >> 16) & 1u)) >> 16);
}
__device__ __forceinline__ float b2f_lo(unsigned int v){   // low ushort -> float
  return __uint_as_float(v << 16);
}
__device__ __forceinline__ float b2f_hi(unsigned int v){   // high ushort -> float
  return __uint_as_float(v & 0xFFFF0000u);
}
__device__ __forceinline__ int rfl(int v){ return __builtin_amdgcn_readfirstlane(v); }
// shifted softplus via v_exp/v_log (both base-2 on gfx950)
__device__ __forceinline__ float actf(float v){
  float e = __builtin_amdgcn_exp2f(-fabsf(v)*1.44269504088896341f);
  return fmaxf(v, 0.f) + __builtin_amdgcn_logf(1.f + e)*0.69314718055994531f - 0.69314718055994531f;
}

// ---------- small utility kernels ----------
__global__ __launch_bounds__(256) void k_zero(float* p, int n){
  int i = blockIdx.x*256 + threadIdx.x;
  if (i < n) p[i] = 0.f;
}

__global__ __launch_bounds__(256) void k_dij_count(
    const float* __restrict__ R, const int* __restrict__ idx_i, const int* __restrict__ idx_j,
    float* __restrict__ DijF, float* __restrict__ Dout, int* __restrict__ counts, int P){
  int p = blockIdx.x*256 + threadIdx.x;
  if (p >= P) return;
  int i = idx_i[p], j = idx_j[p];
  float dx = R[i*3+0] - R[j*3+0];
  float dy = R[i*3+1] - R[j*3+1];
  float dz = R[i*3+2] - R[j*3+2];
  float D = sqrtf(fmaxf(dx*dx + dy*dy + dz*dz, 0.f));
  DijF[p] = D;
  Dout[p] = D;
  atomicAdd(&counts[i], 1);
}

// single-kernel exclusive scan of counts -> cursor
__global__ __launch_bounds__(1024) void k_scan(const int* __restrict__ counts,
    int* __restrict__ cursor, int N){
  __shared__ int wsum[16];
  int tid = threadIdx.x;
  int CH = (N + 1023) >> 10;
  int base = tid * CH;
  int s = 0;
  for (int i = 0; i < CH; ++i){
    int idx = base + i;
    s += (idx < N) ? counts[idx] : 0;
  }
  int lane = tid & 63, w = tid >> 6;
  int v = s;
  #pragma unroll
  for (int off = 1; off < 64; off <<= 1){
    int t = __shfl_up(v, off, 64);
    if (lane >= off) v += t;
  }
  if (lane == 63) wsum[w] = v;
  __syncthreads();
  if (tid < 16){
    int t = wsum[tid];
    int vv = t;
    #pragma unroll
    for (int off = 1; off < 16; off <<= 1){
      int u = __shfl_up(vv, off, 64);
      if (tid >= off) vv += u;
    }
    wsum[tid] = vv - t;   // exclusive wave offset
  }
  __syncthreads();
  int run = (v - s) + wsum[w];
  for (int i = 0; i < CH; ++i){
    int idx = base + i;
    if (idx < N){ cursor[idx] = run; run += counts[idx]; }
  }
}

__global__ __launch_bounds__(256) void k_scatter(const int* __restrict__ idx_i,
    const int* __restrict__ idx_j, const float* __restrict__ DijF,
    int* __restrict__ cursor, int* __restrict__ i_s, int* __restrict__ j_s,
    float* __restrict__ D_s, int P){
  int p = blockIdx.x*256 + threadIdx.x;
  if (p >= P) return;
  int i = idx_i[p];
  int pos = atomicAdd(&cursor[i], 1);
  i_s[pos] = i;
  j_s[pos] = idx_j[p];
  D_s[pos] = DijF[p];
}
// after k_scatter: cursor[i] == end offset of atom i (CSR ends)

// MERGED: rbf expansion (gid < P*8) + all weight repacks (gid >= P*8).
__global__ __launch_bounds__(256) void k_prep2(
    const float* __restrict__ D_s, const float* __restrict__ cent, const float* __restrict__ wid,
    unsigned short* __restrict__ rbf_s,
    const float* __restrict__ riW1, const float* __restrict__ riW2,
    const float* __restrict__ dW,   const float* __restrict__ raW1,
    const float* __restrict__ raW2, const float* __restrict__ roW1,
    const float* __restrict__ roW2, const float* __restrict__ Wi,
    const float* __restrict__ Wj,   const float* __restrict__ k2f,
    const float* __restrict__ outW,
    unsigned short* __restrict__ WBall, unsigned short* __restrict__ k2fP,
    unsigned short* __restrict__ outWB, int P){
  int gid0 = blockIdx.x*256 + threadIdx.x;
  if (gid0 < P*8){
    int t = gid0 >> 3, kg = gid0 & 7;
    float D = D_s[t];
    float xc = D * 0.1f;
    float cut = 0.f;
    if (xc < 1.f){
      float x3 = xc*xc*xc, x4 = x3*xc, x5 = x4*xc;
      cut = 1.f - 6.f*x5 + 15.f*x4 - 10.f*x3;
    }
    float eD = __builtin_amdgcn_exp2f(-D*1.44269504088896341f);
    bfrag o;
    #pragma unroll
    for (int i = 0; i < 8; ++i){
      int k = kg*8 + i;
      float tt = eD - cent[k];
      float v = cut * __builtin_amdgcn_exp2f(-wid[k]*tt*tt*1.44269504088896341f);
      o[i] = (short)f2b(v);
    }
    *(bfrag*)(rbf_s + (size_t)gid0*8) = o;
    return;
  }
  int gid = gid0 - P*8;
  if (gid < 75*2048){
    int i = gid >> 11, r = gid & 2047;
    const float* S;
    int slot;
    if (i < 15)      { S = riW1 + (size_t)i*16384;      slot = (i/3)*15 + 2*(i%3); }
    else if (i < 30) { int j=i-15; S = riW2 + (size_t)j*16384; slot = (j/3)*15 + 2*(j%3) + 1; }
    else if (i < 35) { int j=i-30; S = dW   + (size_t)j*16384; slot = j*15 + 6; }
    else if (i < 45) { int j=i-35; S = raW1 + (size_t)j*16384; slot = (j/2)*15 + 7 + 2*(j%2); }
    else if (i < 55) { int j=i-45; S = raW2 + (size_t)j*16384; slot = (j/2)*15 + 8 + 2*(j%2); }
    else if (i < 60) { int j=i-55; S = roW1 + (size_t)j*16384; slot = j*15 + 11; }
    else if (i < 65) { int j=i-60; S = roW2 + (size_t)j*16384; slot = j*15 + 12; }
    else if (i < 70) { int j=i-65; S = Wi   + (size_t)j*16384; slot = ((j==0)?4:(j-1))*15 + 13; }
    else             { int j=i-70; S = Wj   + (size_t)j*16384; slot = ((j==0)?4:(j-1))*15 + 14; }
    int fr = r >> 6, l = r & 63;
    int T = fr >> 2, k0 = fr & 3;
    int n = T*16 + (l & 15);
    int kbase = k0*32 + (l >> 4)*8;
    unsigned short* D = WBall + ((size_t)slot*2048 + r)*8;
    ushort4 o0, o1;
    o0.x=f2b(S[(kbase+0)*128+n]); o0.y=f2b(S[(kbase+1)*128+n]);
    o0.z=f2b(S[(kbase+2)*128+n]); o0.w=f2b(S[(kbase+3)*128+n]);
    o1.x=f2b(S[(kbase+4)*128+n]); o1.y=f2b(S[(kbase+5)*128+n]);
    o1.z=f2b(S[(kbase+6)*128+n]); o1.w=f2b(S[(kbase+7)*128+n]);
    ((ushort4*)D)[0]=o0; ((ushort4*)D)[1]=o1;
  } else if (gid < 75*2048 + 5120){
    int g = gid - 75*2048;
    int l = g & 63, fr = (g >> 6) & 15, b = g >> 10;
    int tile = fr >> 1, kh = fr & 1;
    const float* src = k2f + (size_t)b*64*128;
    int n = tile*16 + (l & 15);
    int kbase = kh*32 + (l >> 4)*8;
    ushort4 o0, o1;
    o0.x = f2b(src[(kbase+0)*128+n]); o0.y = f2b(src[(kbase+1)*128+n]);
    o0.z = f2b(src[(kbase+2)*128+n]); o0.w = f2b(src[(kbase+3)*128+n]);
    o1.x = f2b(src[(kbase+4)*128+n]); o1.y = f2b(src[(kbase+5)*128+n]);
    o1.z = f2b(src[(kbase+6)*128+n]); o1.w = f2b(src[(kbase+7)*128+n]);
    ushort4* dst = (ushort4*)(k2fP + (size_t)g*8);
    dst[0] = o0; dst[1] = o1;
  } else if (gid < 75*2048 + 5120 + 1280){
    int g = gid - (75*2048 + 5120);
    int b = g >> 8, r = g & 255;
    int l = r & 63;
    int col = l & 15;
    int k0 = r >> 6;
    int kbase = k0*32 + (l >> 4)*8;
    ushort4 o0 = {0,0,0,0}, o1 = {0,0,0,0};
    if (col < 2){
      const float* S = outW + (size_t)b*256;
      o0.x=f2b(S[(kbase+0)*2+col]); o0.y=f2b(S[(kbase+1)*2+col]);
      o0.z=f2b(S[(kbase+2)*2+col]); o0.w=f2b(S[(kbase+3)*2+col]);
      o1.x=f2b(S[(kbase+4)*2+col]); o1.y=f2b(S[(kbase+5)*2+col]);
      o1.z=f2b(S[(kbase+6)*2+col]); o1.w=f2b(S[(kbase+7)*2+col]);
    }
    unsigned short* D = outWB + ((size_t)b*256 + r)*8;
    ((ushort4*)D)[0]=o0; ((ushort4*)D)[1]=o1;
  }
}

// ---------- MFMA tile machinery ----------
__device__ __forceinline__ void mmtile(const unsigned short* tile,
    const unsigned short* __restrict__ WB, int w, int l, ffrag C[4]){
  int m = l & 15, q = l >> 4;
  bfrag A[4];
  #pragma unroll
  for (int k0 = 0; k0 < 4; ++k0)
    A[k0] = *(const bfrag*)(tile + m*136 + k0*32 + q*8);
  #pragma unroll
  for (int tt = 0; tt < 4; ++tt){
    ffrag c = {0.f,0.f,0.f,0.f};
    const bfrag* bp = (const bfrag*)(WB + (((w*4+tt)*4)*64 + l)*8);
    #pragma unroll
    for (int k0 = 0; k0 < 4; ++k0)
      c = __builtin_amdgcn_mfma_f32_16x16x32_bf16(A[k0], bp[k0*64], c, 0, 0, 0);
    C[tt] = c;
  }
}

// phase1: x = emb[Z]; m_g = xi = act(act(x)@Wi0+bi0); xjbA = act(act(x)@Wj0+bj0) [bf16]
__global__ __launch_bounds__(128) void k_phase1m(
    const int* __restrict__ Z, const float* __restrict__ emb,
    const unsigned short* __restrict__ WB45,
    const float* __restrict__ bi0, const float* __restrict__ bj0,
    float* __restrict__ x_g, float* __restrict__ m_g, unsigned short* __restrict__ xjb_g, int N){
  __shared__ unsigned short tile[16*136];
  int tid = threadIdx.x, w = tid >> 6, l = tid & 63;
  int m = l & 15, q = l >> 4, rbase = blockIdx.x*16;
  #pragma unroll
  for (int r = 0; r < 4; ++r){
    int row = rbase + q*4 + r;
    int z = Z[row];
    #pragma unroll
    for (int tt = 0; tt < 4; ++tt){
      int c = (w*4+tt)*16 + m;
      float v = emb[(size_t)z*128 + c];
      x_g[(size_t)row*128 + c] = v;
      tile[(q*4+r)*136 + c] = f2b(actf(v));
    }
  }
  __syncthreads();
  ffrag C[4];
  mmtile(tile, WB45 + 13*16384, w, l, C);
  #pragma unroll
  for (int tt = 0; tt < 4; ++tt){
    int c = (w*4+tt)*16 + m;
    float bb = bi0[c];
    #pragma unroll
    for (int r = 0; r < 4; ++r)
      m_g[(size_t)(rbase + q*4 + r)*128 + c] = actf(C[tt][r] + bb);
  }
  mmtile(tile, WB45 + 14*16384, w, l, C);
  #pragma unroll
  for (int tt = 0; tt < 4; ++tt){
    int c = (w*4+tt)*16 + m;
    float bb = bj0[c];
    #pragma unroll
    for (int r = 0; r < 4; ++r)
      xjb_g[(size_t)(rbase + q*4 + r)*128 + c] = f2b(actf(C[tt][r] + bb));
  }
}

// ---------- FUSED per-b kernel: CSR-local pair phase + 16-row dense chain ----------
// Block owns 16 atoms; pairs counting-sorted by i -> contiguous range
// [ends[rbase-1], ends[rbase+15]). 8 waves process 16-aligned batches (stride 8);
// boundary batches filtered by the i-range guard (disjoint, no double count).
// Messages reduce via LDS atomics into mL[16][128] -> ZERO global atomics, no
// m round-trip. Dense phase = R11's measured-best 16-row body, S0 = m_g + mL.
// xjb ping-pongs across b (read prev buffer) -> no cross-block race.
// LDS: G 66560 + mL 8192 = 74752 B -> 2 blocks/CU (149.5KB <= 160KB).
// VGPR: pair ~84 (scoped B[16]) / dense ~85 -> max ~115 < (512,4) cap 128.
template<int HASNEXT, int NH>
__global__ __launch_bounds__(512, 4) void k_block2(
    const unsigned short* __restrict__ rbf_s, const unsigned short* __restrict__ k2fP,
    const int* __restrict__ i_s, const int* __restrict__ j_s,
    const int* __restrict__ ends,
    const unsigned short* __restrict__ xjb_r, unsigned short* __restrict__ xjb_w,
    float* __restrict__ m_g, float* __restrict__ x_g,
    const unsigned short* __restrict__ WBb,
    const float* __restrict__ rib1, const float* __restrict__ rib2,
    const float* __restrict__ db, const float* __restrict__ u,
    const float* __restrict__ rab1, const float* __restrict__ rab2,
    const float* __restrict__ rob1, const float* __restrict__ rob2,
    const float* __restrict__ biN, const float* __restrict__ bjN,
    const unsigned short* __restrict__ outWBb,
    float* __restrict__ Ea, float* __restrict__ Qa,
    float* __restrict__ last2, float* __restrict__ nh, int N, int P){
  __shared__ float G[8][16*130];                       // 66560 B (pair scratch)
  __shared__ float mL[16*128];                         //  8192 B (message accum)
  unsigned short* tilesS = (unsigned short*)&G[0][0];  // dense tiles[2][16*136] (8704 B)
  float* biasS = (float*)((char*)&G[0][0] + 8704);     // dense bias 16*128 f32 (8192 B)
  int tid = threadIdx.x, w = tid >> 6, l = tid & 63;
  int m = l & 15, q = l >> 4, rbase = blockIdx.x*16;
  int c = w*16 + m;
  #pragma unroll
  for (int i = tid; i < 2048; i += 512) mL[i] = 0.f;
  __syncthreads();
  // ================= pair phase =================
  {
    float* Gw = &G[w][0];
    bfrag B[16];
    #pragma unroll
    for (int t = 0; t < 16; ++t)
      B[t] = *(const bfrag*)(k2fP + (size_t)(t*64 + l)*8);
    int pstart = (rbase == 0) ? 0 : ends[rbase-1];
    int pend   = ends[rbase+15];
    int b0 = pstart >> 4, b1 = (pend + 15) >> 4;   // global 16-aligned batches
    float a0 = 0.f, a1 = 0.f;
    int iCur = -1;
    #pragma unroll 1
    for (int bt = b0 + w; bt < b1; bt += 8){
      int base = bt << 4;
      // A-frags: sequential rbf stream
      bfrag A0 = *(const bfrag*)(rbf_s + (size_t)(base + m)*64 + q*8);
      bfrag A1 = *(const bfrag*)(rbf_s + (size_t)(base + m)*64 + 32 + q*8);
      // wave-uniform indices -> SGPRs
      int ip[16], jp[16];
      #pragma unroll
      for (int g = 0; g < 4; ++g){
        int4 it = *(const int4*)(i_s + base + g*4);
        int4 jt = *(const int4*)(j_s + base + g*4);
        ip[g*4+0]=rfl(it.x); ip[g*4+1]=rfl(it.y); ip[g*4+2]=rfl(it.z); ip[g*4+3]=rfl(it.w);
        jp[g*4+0]=rfl(jt.x); jp[g*4+1]=rfl(jt.y); jp[g*4+2]=rfl(jt.z); jp[g*4+3]=rfl(jt.w);
      }
      // issue gathers BEFORE the MFMA block (latency hides under MFMA)
      unsigned int xv[16];
      #pragma unroll
      for (int k = 0; k < 16; ++k)
        xv[k] = *(const unsigned int*)(xjb_r + (size_t)jp[k]*128 + 2*l);
      #pragma unroll
      for (int t = 0; t < 8; ++t){
        ffrag C = {0.f,0.f,0.f,0.f};
        C = __builtin_amdgcn_mfma_f32_16x16x32_bf16(A0, B[t*2],   C, 0, 0, 0);
        C = __builtin_amdgcn_mfma_f32_16x16x32_bf16(A1, B[t*2+1], C, 0, 0, 0);
        #pragma unroll
        for (int r = 0; r < 4; ++r)
          Gw[(q*4+r)*130 + t*16 + m] = C[r];
      }
      #pragma unroll
      for (int k = 0; k < 16; ++k){
        int i = ip[k];
        if ((unsigned)(i - rbase) < 16u){
          if (i != iCur){
            if (iCur >= 0){
              atomicAdd(&mL[(iCur-rbase)*128 + 2*l],     a0);
              atomicAdd(&mL[(iCur-rbase)*128 + 2*l + 1], a1);
            }
            iCur = i; a0 = 0.f; a1 = 0.f;
          }
          float g0 = Gw[k*130 + 2*l], g1 = Gw[k*130 + 2*l + 1];
          a0 = fmaf(g0, b2f_lo(xv[k]), a0);
          a1 = fmaf(g1, b2f_hi(xv[k]), a1);
        }
      }
    }
    if (iCur >= 0){
      atomicAdd(&mL[(iCur-rbase)*128 + 2*l],     a0);
      atomicAdd(&mL[(iCur-rbase)*128 + 2*l + 1], a1);
    }
  }
  __syncthreads();   // mL final; G region dead -> reuse for tiles/bias
  // ================= dense phase (R11 16-row body) =================
  if (tid < 128){
    biasS[0*128+tid]  = rib1[tid];
    biasS[1*128+tid]  = rib1[128+tid];
    biasS[2*128+tid]  = rib1[256+tid];
    biasS[3*128+tid]  = rib2[tid];
    biasS[4*128+tid]  = rib2[128+tid];
    biasS[5*128+tid]  = rib2[256+tid];
    biasS[6*128+tid]  = db[tid];
    biasS[7*128+tid]  = u[tid];
    biasS[8*128+tid]  = rab1[tid];
    biasS[9*128+tid]  = rab1[128+tid];
    biasS[10*128+tid] = rab2[tid];
    biasS[11*128+tid] = rab2[128+tid];
    biasS[12*128+tid] = rob1[tid];
    biasS[13*128+tid] = rob2[tid];
    biasS[14*128+tid] = biN[tid];
    biasS[15*128+tid] = bjN[tid];
  }
  ffrag mC, xC, C;
  float xrow[4];
  int cur = 0;
  const int nst = HASNEXT ? 15 : 13;
  const int slotSeq[15] = {0,1,2,3,4,5,6,7,8,9,10,
                           HASNEXT?13:11, HASNEXT?14:12, 11, 12};
  bfrag Bb[2][4];
  #pragma unroll
  for (int k0 = 0; k0 < 4; ++k0)
    Bb[0][k0] = *(const bfrag*)(WBb + (size_t)slotSeq[0]*16384 + (size_t)((w*4+k0)*64 + l)*8);
  // S0: m = xi (m_g) + LDS messages; tiles[0] = act(m); preload x rows
  #pragma unroll
  for (int r = 0; r < 4; ++r){
    int row = rbase + q*4 + r;
    xrow[r] = x_g[(size_t)row*128 + c];
    float v = m_g[(size_t)row*128 + c] + mL[(q*4+r)*128 + c];
    mC[r] = v;
    tilesS[(q*4+r)*136 + c] = f2b(actf(v));
  }
  #pragma unroll 2
  for (int s = 0; s < nst; ++s){
    __syncthreads();
    if (s+1 < nst){
      #pragma unroll
      for (int k0 = 0; k0 < 4; ++k0)
        Bb[(s+1)&1][k0] = *(const bfrag*)(WBb + (size_t)slotSeq[s+1]*16384 + (size_t)((w*4+k0)*64 + l)*8);
    }
    {
      const unsigned short* tp = tilesS + cur*2176;
      ffrag cc = {0.f,0.f,0.f,0.f};
      #pragma unroll
      for (int k0 = 0; k0 < 4; ++k0){
        bfrag A = *(const bfrag*)(tp + m*136 + k0*32 + q*8);
        cc = __builtin_amdgcn_mfma_f32_16x16x32_bf16(A, Bb[s&1][k0], cc, 0, 0, 0);
      }
      C = cc;
    }
    if (HASNEXT && s == 11){            // WiN -> m_g (= xi for next block)
      float bb = biasS[14*128 + c];
      #pragma unroll
      for (int r = 0; r < 4; ++r)
        m_g[(size_t)(rbase + q*4 + r)*128 + c] = actf(C[r] + bb);
    } else if (HASNEXT && s == 12){     // WjN -> xjb_w (bf16) for next block
      float bb = biasS[15*128 + c];
      #pragma unroll
      for (int r = 0; r < 4; ++r)
        xjb_w[(size_t)(rbase + q*4 + r)*128 + c] = f2b(actf(C[r] + bb));
    } else if (s == 6){                 // x-update
      float uu = biasS[7*128 + c], bb = biasS[6*128 + c];
      #pragma unroll
      for (int r = 0; r < 4; ++r){
        float nv = uu*xrow[r] + C[r] + bb;
        xC[r] = nv;
        tilesS[(1-cur)*2176 + (q*4+r)*136 + c] = f2b(actf(nv));
      }
      cur ^= 1;
    } else if (s == 1 || s == 3 || s == 5){   // m-residual close
      float bb = biasS[(3 + (s>>1))*128 + c];
      #pragma unroll
      for (int r = 0; r < 4; ++r){
        float nv = mC[r] + C[r] + bb;
        mC[r] = nv;
        tilesS[(1-cur)*2176 + (q*4+r)*136 + c] = f2b(actf(nv));
      }
      cur ^= 1;
    } else if (s == 8 || s == 10){            // x-residual close
      float bb = biasS[(10 + ((s-8)>>1))*128 + c];
      #pragma unroll
      for (int r = 0; r < 4; ++r){
        float nv = xC[r] + C[r] + bb;
        xC[r] = nv;
        tilesS[(1-cur)*2176 + (q*4+r)*136 + c] = f2b(actf(nv));
        if (HASNEXT && s == 10)
          x_g[(size_t)(rbase + q*4 + r)*128 + c] = nv;
      }
      cur ^= 1;
    } else if ((HASNEXT && s == 14) || (!HASNEXT && s == 12)){  // o = x + h@roW2 + b
      float bb = biasS[13*128 + c];
      #pragma unroll
      for (int r = 0; r < 4; ++r){
        float ov = xC[r] + C[r] + bb;
        tilesS[(1-cur)*2176 + (q*4+r)*136 + c] = f2b(actf(ov));
      }
      cur ^= 1;
    } else {                                  // act-only stages
      int bidx = (s==0)?0:(s==2)?1:(s==4)?2:(s==7)?8:(s==9)?9:12;
      float bb = biasS[bidx*128 + c];
      #pragma unroll
      for (int r = 0; r < 4; ++r)
        tilesS[(1-cur)*2176 + (q*4+r)*136 + c] = f2b(actf(C[r] + bb));
      cur ^= 1;
    }
  }
  // head: out = act(o) @ outW (padded to 16 cols), wave 0 only
  __syncthreads();
  if (w == 0){
    const unsigned short* tp = tilesS + cur*2176;
    bfrag A[4];
    #pragma unroll
    for (int k0 = 0; k0 < 4; ++k0)
      A[k0] = *(const bfrag*)(tp + m*136 + k0*32 + q*8);
    ffrag Ch = {0.f,0.f,0.f,0.f};
    #pragma unroll
    for (int k0 = 0; k0 < 4; ++k0){
      bfrag B = *(const bfrag*)(outWBb + (size_t)(k0*64 + l)*8);
      Ch = __builtin_amdgcn_mfma_f32_16x16x32_bf16(A[k0], B, Ch, 0, 0, 0);
    }
    int col = m;
    if (col < 2){
      float tpa = 0.f;
      #pragma unroll
      for (int r = 0; r < 4; ++r){
        int row = rbase + q*4 + r;
        float val = Ch[r];
        if (NH){
          if (col == 0) Ea[row] += val; else Qa[row] += val;
        } else {
          if (col == 0) Ea[row]  = val; else Qa[row]  = val;
        }
        float sq = val*val;
        if (NH){
          float lastv = last2[row*2 + col];
          tpa += sq/(sq + lastv + 1e-7f);
        }
        last2[row*2 + col] = sq;
      }
      if (NH) unsafeAtomicAdd(nh, tpa);
    }
  }
}

__global__ __launch_bounds__(256) void k_final(
    const int* __restrict__ Z, const float* __restrict__ Ea, const float* __restrict__ Qa,
    const float* __restrict__ Es, const float* __restrict__ Eh,
    const float* __restrict__ Qs, const float* __restrict__ Qh,
    const float* __restrict__ nh, float* __restrict__ out, int N, int P){
  int n = blockIdx.x*256 + threadIdx.x;
  if (n < N){
    int z = Z[n];
    out[n]   = Es[z]*Ea[n] + Eh[z];
    out[N+n] = Qs[z]*Qa[n] + Qh[z];
  }
  if (blockIdx.x == 0 && threadIdx.x == 0)
    out[(size_t)2*N + P] = nh[0] / (2.f * (float)N);
}

extern "C" void kernel_launch(void* const* d_in, const int* in_sizes, int n_in,
                              void* d_out, int out_size, void* d_ws, size_t ws_size,
                              hipStream_t stream){
  const int N = in_sizes[0];
  const int P = in_sizes[2];
  const int F = 128;

  const int* Z      = (const int*)d_in[0];
  const float* R    = (const float*)d_in[1];
  const int* idx_i  = (const int*)d_in[2];
  const int* idx_j  = (const int*)d_in[3];
  const float* emb  = (const float*)d_in[4];
  const float* cent = (const float*)d_in[5];
  const float* wid  = (const float*)d_in[6];
  const float* k2f  = (const float*)d_in[7];
  const float* Wi   = (const float*)d_in[8];  const float* bi   = (const float*)d_in[9];
  const float* Wj   = (const float*)d_in[10]; const float* bj   = (const float*)d_in[11];
  const float* riW1 = (const float*)d_in[12]; const float* rib1 = (const float*)d_in[13];
  const float* riW2 = (const float*)d_in[14]; const float* rib2 = (const float*)d_in[15];
  const float* dWp  = (const float*)d_in[16]; const float* dbp  = (const float*)d_in[17];
  const float* u    = (const float*)d_in[18];
  const float* raW1 = (const float*)d_in[19]; const float* rab1 = (const float*)d_in[20];
  const float* raW2 = (const float*)d_in[21]; const float* rab2 = (const float*)d_in[22];
  const float* roW1 = (const float*)d_in[23]; const float* rob1 = (const float*)d_in[24];
  const float* roW2 = (const float*)d_in[25]; const float* rob2 = (const float*)d_in[26];
  const float* outW = (const float*)d_in[27];
  const float* Es   = (const float*)d_in[28]; const float* Eh   = (const float*)d_in[29];
  const float* Qs   = (const float*)d_in[30]; const float* Qh   = (const float*)d_in[31];

  char* ws = (char*)d_ws;
  size_t off = 0;
  float* DijF  = (float*)(ws + off); off += (size_t)P*4;
  float* D_s   = (float*)(ws + off); off += (size_t)P*4;
  int*   i_s   = (int*)  (ws + off); off += (size_t)P*4;
  int*   j_s   = (int*)  (ws + off); off += (size_t)P*4;
  unsigned short* rbf_s = (unsigned short*)(ws + off); off += (size_t)P*64*2;
  unsigned short* k2fP  = (unsigned short*)(ws + off); off += (size_t)5*16*64*8*2;
  unsigned short* WBall = (unsigned short*)(ws + off); off += (size_t)75*16384*2;
  unsigned short* outWB = (unsigned short*)(ws + off); off += (size_t)5*2048*2;
  float* x     = (float*)(ws + off); off += (size_t)N*F*4;
  unsigned short* xjbA = (unsigned short*)(ws + off); off += (size_t)N*F*2;
  unsigned short* xjbB = (unsigned short*)(ws + off); off += (size_t)N*F*2;
  float* m     = (float*)(ws + off); off += (size_t)N*F*4;
  float* last2 = (float*)(ws + off); off += (size_t)N*2*4;
  float* Ea    = (float*)(ws + off); off += (size_t)N*4;
  float* Qa    = (float*)(ws + off); off += (size_t)N*4;
  float* nh    = (float*)(ws + off); off += 256;          // zero region start (nh)
  int*   counts= (int*)  (ws + off); off += (size_t)N*4;  // zero region end
  int*   cursor= (int*)  (ws + off); off += (size_t)N*4;  // CSR ends after scatter

  float* outF = (float*)d_out;
  float* Dout = outF + (size_t)2*N;

  const int nzero = N + 64;
  k_zero<<<dim3((nzero+255)/256), dim3(256), 0, stream>>>(nh, nzero);
  k_dij_count<<<dim3((P+255)/256), dim3(256), 0, stream>>>(R, idx_i, idx_j, DijF, Dout, counts, P);
  k_scan<<<dim3(1), dim3(1024), 0, stream>>>(counts, cursor, N);
  k_scatter<<<dim3((P+255)/256), dim3(256), 0, stream>>>(idx_i, idx_j, DijF, cursor, i_s, j_s, D_s, P);
  const int prep2n = P*8 + 75*2048 + 5120 + 1280;
  k_prep2<<<dim3((prep2n+255)/256), dim3(256), 0, stream>>>(
      D_s, cent, wid, rbf_s,
      riW1, riW2, dWp, raW1, raW2, roW1, roW2, Wi, Wj, k2f, outW,
      WBall, k2fP, outWB, P);

  const int G16 = (N + 15)/16;
  k_phase1m<<<dim3(G16), dim3(128), 0, stream>>>(Z, emb, WBall + (size_t)4*15*16384,
                                                 bi, bj, x, m, xjbA, N);

  for (int b = 0; b < 5; ++b){
    const unsigned short* WBb = WBall + (size_t)b*15*16384;
    const float* a_rib1 = rib1 + (size_t)b*3*F;
    const float* a_rib2 = rib2 + (size_t)b*3*F;
    const float* a_db   = dbp  + (size_t)b*F;
    const float* a_u    = u    + (size_t)b*F;
    const float* a_rab1 = rab1 + (size_t)b*2*F;
    const float* a_rab2 = rab2 + (size_t)b*2*F;
    const float* a_rob1 = rob1 + (size_t)b*F;
    const float* a_rob2 = rob2 + (size_t)b*F;
    int bn = (b < 4) ? (b+1) : 0;
    const float* a_biN = bi + (size_t)bn*F;
    const float* a_bjN = bj + (size_t)bn*F;
    const unsigned short* oWB = outWB + (size_t)b*2048;
    const unsigned short* kP  = k2fP + (size_t)b*16*64*8;
    const unsigned short* xr  = (b & 1) ? xjbB : xjbA;
    unsigned short*       xw  = (b & 1) ? xjbA : xjbB;
    if (b == 0){
      k_block2<1,0><<<dim3(G16), dim3(512), 0, stream>>>(rbf_s, kP, i_s, j_s, cursor,
        xr, xw, m, x, WBb, a_rib1, a_rib2, a_db, a_u, a_rab1, a_rab2, a_rob1, a_rob2,
        a_biN, a_bjN, oWB, Ea, Qa, last2, nh, N, P);
    } else if (b < 4){
      k_block2<1,1><<<dim3(G16), dim3(512), 0, stream>>>(rbf_s, kP, i_s, j_s, cursor,
        xr, xw, m, x, WBb, a_rib1, a_rib2, a_db, a_u, a_rab1, a_rab2, a_rob1, a_rob2,
        a_biN, a_bjN, oWB, Ea, Qa, last2, nh, N, P);
    } else {
      k_block2<0,1><<<dim3(G16), dim3(512), 0, stream>>>(rbf_s, kP, i_s, j_s, cursor,
        xr, xw, m, x, WBb, a_rib1, a_rib2, a_db, a_u, a_rab1, a_rab2, a_rob1, a_rob2,
        a_biN, a_bjN, oWB, Ea, Qa, last2, nh, N, P);
    }
  }
  k_final<<<dim3((N+255)/256), dim3(256), 0, stream>>>(Z, Ea, Qa, Es, Eh, Qs, Qh, nh, outF, N, P);
}

// Round 13
// 441.844 us; speedup vs baseline: 1.1309x; 1.1309x over previous
//
#include <hip/hip_runtime.h>

typedef __attribute__((ext_vector_type(8))) short bfrag;   // 8 bf16 (4 VGPRs)
typedef __attribute__((ext_vector_type(4))) float ffrag;   // 4 fp32

__device__ __forceinline__ unsigned short f2b(float f){
  unsigned int u = __float_as_uint(f);
  return (unsigned short)((u + 0x7FFFu + ((u >> 16) & 1u)) >> 16);
}
__device__ __forceinline__ float b2f_lo(unsigned int v){   // low ushort -> float
  return __uint_as_float(v << 16);
}
__device__ __forceinline__ float b2f_hi(unsigned int v){   // high ushort -> float
  return __uint_as_float(v & 0xFFFF0000u);
}
__device__ __forceinline__ int rfl(int v){ return __builtin_amdgcn_readfirstlane(v); }
// shifted softplus via v_exp/v_log (both base-2 on gfx950)
__device__ __forceinline__ float actf(float v){
  float e = __builtin_amdgcn_exp2f(-fabsf(v)*1.44269504088896341f);
  return fmaxf(v, 0.f) + __builtin_amdgcn_logf(1.f + e)*0.69314718055994531f - 0.69314718055994531f;
}

// ---------- small utility kernels ----------
__global__ __launch_bounds__(256) void k_zero(float* p, int n){
  int i = blockIdx.x*256 + threadIdx.x;
  if (i < n) p[i] = 0.f;
}

__global__ __launch_bounds__(256) void k_dij_count(
    const float* __restrict__ R, const int* __restrict__ idx_i, const int* __restrict__ idx_j,
    float* __restrict__ DijF, float* __restrict__ Dout, int* __restrict__ counts, int P){
  int p = blockIdx.x*256 + threadIdx.x;
  if (p >= P) return;
  int i = idx_i[p], j = idx_j[p];
  float dx = R[i*3+0] - R[j*3+0];
  float dy = R[i*3+1] - R[j*3+1];
  float dz = R[i*3+2] - R[j*3+2];
  float D = sqrtf(fmaxf(dx*dx + dy*dy + dz*dz, 0.f));
  DijF[p] = D;
  Dout[p] = D;
  atomicAdd(&counts[i], 1);
}

// single-kernel exclusive scan of counts -> cursor
__global__ __launch_bounds__(1024) void k_scan(const int* __restrict__ counts,
    int* __restrict__ cursor, int N){
  __shared__ int wsum[16];
  int tid = threadIdx.x;
  int CH = (N + 1023) >> 10;
  int base = tid * CH;
  int s = 0;
  for (int i = 0; i < CH; ++i){
    int idx = base + i;
    s += (idx < N) ? counts[idx] : 0;
  }
  int lane = tid & 63, w = tid >> 6;
  int v = s;
  #pragma unroll
  for (int off = 1; off < 64; off <<= 1){
    int t = __shfl_up(v, off, 64);
    if (lane >= off) v += t;
  }
  if (lane == 63) wsum[w] = v;
  __syncthreads();
  if (tid < 16){
    int t = wsum[tid];
    int vv = t;
    #pragma unroll
    for (int off = 1; off < 16; off <<= 1){
      int u = __shfl_up(vv, off, 64);
      if (tid >= off) vv += u;
    }
    wsum[tid] = vv - t;   // exclusive wave offset
  }
  __syncthreads();
  int run = (v - s) + wsum[w];
  for (int i = 0; i < CH; ++i){
    int idx = base + i;
    if (idx < N){ cursor[idx] = run; run += counts[idx]; }
  }
}

__global__ __launch_bounds__(256) void k_scatter(const int* __restrict__ idx_i,
    const int* __restrict__ idx_j, const float* __restrict__ DijF,
    int* __restrict__ cursor, int* __restrict__ i_s, int* __restrict__ j_s,
    float* __restrict__ D_s, int P){
  int p = blockIdx.x*256 + threadIdx.x;
  if (p >= P) return;
  int i = idx_i[p];
  int pos = atomicAdd(&cursor[i], 1);
  i_s[pos] = i;
  j_s[pos] = idx_j[p];
  D_s[pos] = DijF[p];
}

// MERGED: rbf expansion (gid < P*8) + all weight repacks (gid >= P*8).
__global__ __launch_bounds__(256) void k_prep2(
    const float* __restrict__ D_s, const float* __restrict__ cent, const float* __restrict__ wid,
    unsigned short* __restrict__ rbf_s,
    const float* __restrict__ riW1, const float* __restrict__ riW2,
    const float* __restrict__ dW,   const float* __restrict__ raW1,
    const float* __restrict__ raW2, const float* __restrict__ roW1,
    const float* __restrict__ roW2, const float* __restrict__ Wi,
    const float* __restrict__ Wj,   const float* __restrict__ k2f,
    const float* __restrict__ outW,
    unsigned short* __restrict__ WBall, unsigned short* __restrict__ k2fP,
    unsigned short* __restrict__ outWB, int P){
  int gid0 = blockIdx.x*256 + threadIdx.x;
  if (gid0 < P*8){
    int t = gid0 >> 3, kg = gid0 & 7;
    float D = D_s[t];
    float xc = D * 0.1f;
    float cut = 0.f;
    if (xc < 1.f){
      float x3 = xc*xc*xc, x4 = x3*xc, x5 = x4*xc;
      cut = 1.f - 6.f*x5 + 15.f*x4 - 10.f*x3;
    }
    float eD = __builtin_amdgcn_exp2f(-D*1.44269504088896341f);
    bfrag o;
    #pragma unroll
    for (int i = 0; i < 8; ++i){
      int k = kg*8 + i;
      float tt = eD - cent[k];
      float v = cut * __builtin_amdgcn_exp2f(-wid[k]*tt*tt*1.44269504088896341f);
      o[i] = (short)f2b(v);
    }
    *(bfrag*)(rbf_s + (size_t)gid0*8) = o;
    return;
  }
  int gid = gid0 - P*8;
  if (gid < 75*2048){
    int i = gid >> 11, r = gid & 2047;
    const float* S;
    int slot;
    if (i < 15)      { S = riW1 + (size_t)i*16384;      slot = (i/3)*15 + 2*(i%3); }
    else if (i < 30) { int j=i-15; S = riW2 + (size_t)j*16384; slot = (j/3)*15 + 2*(j%3) + 1; }
    else if (i < 35) { int j=i-30; S = dW   + (size_t)j*16384; slot = j*15 + 6; }
    else if (i < 45) { int j=i-35; S = raW1 + (size_t)j*16384; slot = (j/2)*15 + 7 + 2*(j%2); }
    else if (i < 55) { int j=i-45; S = raW2 + (size_t)j*16384; slot = (j/2)*15 + 8 + 2*(j%2); }
    else if (i < 60) { int j=i-55; S = roW1 + (size_t)j*16384; slot = j*15 + 11; }
    else if (i < 65) { int j=i-60; S = roW2 + (size_t)j*16384; slot = j*15 + 12; }
    else if (i < 70) { int j=i-65; S = Wi   + (size_t)j*16384; slot = ((j==0)?4:(j-1))*15 + 13; }
    else             { int j=i-70; S = Wj   + (size_t)j*16384; slot = ((j==0)?4:(j-1))*15 + 14; }
    int fr = r >> 6, l = r & 63;
    int T = fr >> 2, k0 = fr & 3;
    int n = T*16 + (l & 15);
    int kbase = k0*32 + (l >> 4)*8;
    unsigned short* D = WBall + ((size_t)slot*2048 + r)*8;
    ushort4 o0, o1;
    o0.x=f2b(S[(kbase+0)*128+n]); o0.y=f2b(S[(kbase+1)*128+n]);
    o0.z=f2b(S[(kbase+2)*128+n]); o0.w=f2b(S[(kbase+3)*128+n]);
    o1.x=f2b(S[(kbase+4)*128+n]); o1.y=f2b(S[(kbase+5)*128+n]);
    o1.z=f2b(S[(kbase+6)*128+n]); o1.w=f2b(S[(kbase+7)*128+n]);
    ((ushort4*)D)[0]=o0; ((ushort4*)D)[1]=o1;
  } else if (gid < 75*2048 + 5120){
    int g = gid - 75*2048;
    int l = g & 63, fr = (g >> 6) & 15, b = g >> 10;
    int tile = fr >> 1, kh = fr & 1;
    const float* src = k2f + (size_t)b*64*128;
    int n = tile*16 + (l & 15);
    int kbase = kh*32 + (l >> 4)*8;
    ushort4 o0, o1;
    o0.x = f2b(src[(kbase+0)*128+n]); o0.y = f2b(src[(kbase+1)*128+n]);
    o0.z = f2b(src[(kbase+2)*128+n]); o0.w = f2b(src[(kbase+3)*128+n]);
    o1.x = f2b(src[(kbase+4)*128+n]); o1.y = f2b(src[(kbase+5)*128+n]);
    o1.z = f2b(src[(kbase+6)*128+n]); o1.w = f2b(src[(kbase+7)*128+n]);
    ushort4* dst = (ushort4*)(k2fP + (size_t)g*8);
    dst[0] = o0; dst[1] = o1;
  } else if (gid < 75*2048 + 5120 + 1280){
    int g = gid - (75*2048 + 5120);
    int b = g >> 8, r = g & 255;
    int l = r & 63;
    int col = l & 15;
    int k0 = r >> 6;
    int kbase = k0*32 + (l >> 4)*8;
    ushort4 o0 = {0,0,0,0}, o1 = {0,0,0,0};
    if (col < 2){
      const float* S = outW + (size_t)b*256;
      o0.x=f2b(S[(kbase+0)*2+col]); o0.y=f2b(S[(kbase+1)*2+col]);
      o0.z=f2b(S[(kbase+2)*2+col]); o0.w=f2b(S[(kbase+3)*2+col]);
      o1.x=f2b(S[(kbase+4)*2+col]); o1.y=f2b(S[(kbase+5)*2+col]);
      o1.z=f2b(S[(kbase+6)*2+col]); o1.w=f2b(S[(kbase+7)*2+col]);
    }
    unsigned short* D = outWB + ((size_t)b*256 + r)*8;
    ((ushort4*)D)[0]=o0; ((ushort4*)D)[1]=o1;
  }
}

// ---------- MFMA tile machinery ----------
__device__ __forceinline__ void mmtile(const unsigned short* tile,
    const unsigned short* __restrict__ WB, int w, int l, ffrag C[4]){
  int m = l & 15, q = l >> 4;
  bfrag A[4];
  #pragma unroll
  for (int k0 = 0; k0 < 4; ++k0)
    A[k0] = *(const bfrag*)(tile + m*136 + k0*32 + q*8);
  #pragma unroll
  for (int tt = 0; tt < 4; ++tt){
    ffrag c = {0.f,0.f,0.f,0.f};
    const bfrag* bp = (const bfrag*)(WB + (((w*4+tt)*4)*64 + l)*8);
    #pragma unroll
    for (int k0 = 0; k0 < 4; ++k0)
      c = __builtin_amdgcn_mfma_f32_16x16x32_bf16(A[k0], bp[k0*64], c, 0, 0, 0);
    C[tt] = c;
  }
}

// phase1: x = emb[Z]; m_g = act(act(x)@Wi0+bi0); xjb = act(act(x)@Wj0+bj0) [bf16]
__global__ __launch_bounds__(128) void k_phase1m(
    const int* __restrict__ Z, const float* __restrict__ emb,
    const unsigned short* __restrict__ WB45,
    const float* __restrict__ bi0, const float* __restrict__ bj0,
    float* __restrict__ x_g, float* __restrict__ m_g, unsigned short* __restrict__ xjb_g, int N){
  __shared__ unsigned short tile[16*136];
  int tid = threadIdx.x, w = tid >> 6, l = tid & 63;
  int m = l & 15, q = l >> 4, rbase = blockIdx.x*16;
  #pragma unroll
  for (int r = 0; r < 4; ++r){
    int row = rbase + q*4 + r;
    int z = Z[row];
    #pragma unroll
    for (int tt = 0; tt < 4; ++tt){
      int c = (w*4+tt)*16 + m;
      float v = emb[(size_t)z*128 + c];
      x_g[(size_t)row*128 + c] = v;
      tile[(q*4+r)*136 + c] = f2b(actf(v));
    }
  }
  __syncthreads();
  ffrag C[4];
  mmtile(tile, WB45 + 13*16384, w, l, C);
  #pragma unroll
  for (int tt = 0; tt < 4; ++tt){
    int c = (w*4+tt)*16 + m;
    float bb = bi0[c];
    #pragma unroll
    for (int r = 0; r < 4; ++r)
      m_g[(size_t)(rbase + q*4 + r)*128 + c] = actf(C[tt][r] + bb);
  }
  mmtile(tile, WB45 + 14*16384, w, l, C);
  #pragma unroll
  for (int tt = 0; tt < 4; ++tt){
    int c = (w*4+tt)*16 + m;
    float bb = bj0[c];
    #pragma unroll
    for (int r = 0; r < 4; ++r)
      xjb_g[(size_t)(rbase + q*4 + r)*128 + c] = f2b(actf(C[tt][r] + bb));
  }
}

// ---------- pair-message v4: cross-batch xv prefetch, B halved ----------
// Diagnosis (R6-R12): gather-latency-bound (~4200cy/batch vs ~400cy issued).
// Fix: issue next batch's gathers AFTER this batch's MFMA so they complete
// under the ~300cy consume + next A-loads. Register budget kept <=~100 live:
// B0[8] persistent (32 VGPR); B1[8] reloaded per batch from L2-resident k2fP
// (transient 32, dead before consume); xv cur+next 32; A 8.
__global__ __launch_bounds__(256, 4) void k_pairmsg2(
    const unsigned short* __restrict__ rbf_s, const unsigned short* __restrict__ k2fP,
    const int* __restrict__ i_s, const int* __restrict__ j_s,
    const unsigned short* __restrict__ xj, float* __restrict__ m_g, int P){
  __shared__ float G[4][16*130];
  int tid = threadIdx.x, w = tid >> 6, l = tid & 63;
  float* Gw = &G[w][0];
  bfrag B0[8];
  #pragma unroll
  for (int t = 0; t < 8; ++t)
    B0[t] = *(const bfrag*)(k2fP + (size_t)(t*64 + l)*8);
  int wstart = (blockIdx.x*4 + w)*64;
  if (wstart >= P) return;
  int row16 = l & 15, quad = l >> 4;
  float a0 = 0.f, a1 = 0.f;
  int iCur = -1;
  // prologue: batch-0 indices + gathers (hide under B0/A loads)
  int ip[16];
  unsigned int xv[16];
  {
    #pragma unroll
    for (int g = 0; g < 4; ++g){
      int4 it = *(const int4*)(i_s + wstart + g*4);
      int4 jt = *(const int4*)(j_s + wstart + g*4);
      ip[g*4+0]=rfl(it.x); ip[g*4+1]=rfl(it.y); ip[g*4+2]=rfl(it.z); ip[g*4+3]=rfl(it.w);
      int jp0=rfl(jt.x), jp1=rfl(jt.y), jp2=rfl(jt.z), jp3=rfl(jt.w);
      xv[g*4+0] = *(const unsigned int*)(xj + (size_t)jp0*128 + 2*l);
      xv[g*4+1] = *(const unsigned int*)(xj + (size_t)jp1*128 + 2*l);
      xv[g*4+2] = *(const unsigned int*)(xj + (size_t)jp2*128 + 2*l);
      xv[g*4+3] = *(const unsigned int*)(xj + (size_t)jp3*128 + 2*l);
    }
  }
  #pragma unroll 1
  for (int bi2 = 0; bi2 < 4; ++bi2){
    int bt = wstart + bi2*16;
    // A-frags: sequential rbf_s stream
    bfrag A0 = *(const bfrag*)(rbf_s + (size_t)(bt + row16)*64 + quad*8);
    bfrag A1 = *(const bfrag*)(rbf_s + (size_t)(bt + row16)*64 + 32 + quad*8);
    // MFMA phase: half0 with persistent B0 while B1 reloads from L2
    {
      bfrag B1[8];
      #pragma unroll
      for (int t = 0; t < 8; ++t)
        B1[t] = *(const bfrag*)(k2fP + (size_t)((8+t)*64 + l)*8);
      #pragma unroll
      for (int t = 0; t < 4; ++t){
        ffrag C = {0.f,0.f,0.f,0.f};
        C = __builtin_amdgcn_mfma_f32_16x16x32_bf16(A0, B0[t*2],   C, 0, 0, 0);
        C = __builtin_amdgcn_mfma_f32_16x16x32_bf16(A1, B0[t*2+1], C, 0, 0, 0);
        #pragma unroll
        for (int r = 0; r < 4; ++r)
          Gw[(quad*4+r)*130 + t*16 + row16] = C[r];
      }
      #pragma unroll
      for (int t = 0; t < 4; ++t){
        ffrag C = {0.f,0.f,0.f,0.f};
        C = __builtin_amdgcn_mfma_f32_16x16x32_bf16(A0, B1[t*2],   C, 0, 0, 0);
        C = __builtin_amdgcn_mfma_f32_16x16x32_bf16(A1, B1[t*2+1], C, 0, 0, 0);
        #pragma unroll
        for (int r = 0; r < 4; ++r)
          Gw[(quad*4+r)*130 + (t+4)*16 + row16] = C[r];
      }
    }
    // prefetch next batch: indices + gathers issued BEFORE consume so the
    // gather latency hides under the consume loop + next batch's A/MFMA
    int ipn[16];
    unsigned int xvn[16];
    if (bi2 < 3){
      int btn = bt + 16;
      #pragma unroll
      for (int g = 0; g < 4; ++g){
        int4 it = *(const int4*)(i_s + btn + g*4);
        int4 jt = *(const int4*)(j_s + btn + g*4);
        ipn[g*4+0]=rfl(it.x); ipn[g*4+1]=rfl(it.y); ipn[g*4+2]=rfl(it.z); ipn[g*4+3]=rfl(it.w);
        int jp0=rfl(jt.x), jp1=rfl(jt.y), jp2=rfl(jt.z), jp3=rfl(jt.w);
        xvn[g*4+0] = *(const unsigned int*)(xj + (size_t)jp0*128 + 2*l);
        xvn[g*4+1] = *(const unsigned int*)(xj + (size_t)jp1*128 + 2*l);
        xvn[g*4+2] = *(const unsigned int*)(xj + (size_t)jp2*128 + 2*l);
        xvn[g*4+3] = *(const unsigned int*)(xj + (size_t)jp3*128 + 2*l);
      }
    }
    // consume current batch
    #pragma unroll
    for (int k = 0; k < 16; ++k){
      int i = ip[k];
      if (i != iCur){
        if (iCur >= 0){
          unsafeAtomicAdd(&m_g[(size_t)iCur*128 + 2*l],     a0);
          unsafeAtomicAdd(&m_g[(size_t)iCur*128 + 2*l + 1], a1);
        }
        iCur = i; a0 = 0.f; a1 = 0.f;
      }
      float g0 = Gw[k*130 + 2*l], g1 = Gw[k*130 + 2*l + 1];
      a0 = fmaf(g0, b2f_lo(xv[k]), a0);
      a1 = fmaf(g1, b2f_hi(xv[k]), a1);
    }
    if (bi2 < 3){
      #pragma unroll
      for (int k = 0; k < 16; ++k){ ip[k] = ipn[k]; xv[k] = xvn[k]; }
    }
  }
  if (iCur >= 0){
    unsafeAtomicAdd(&m_g[(size_t)iCur*128 + 2*l],     a0);
    unsafeAtomicAdd(&m_g[(size_t)iCur*128 + 2*l + 1], a1);
  }
}

// ---------- phase 2: 16 rows/block, 8 waves, 1 col-tile/wave (R11-measured) ----------
template<int HASNEXT, int NH>
__global__ __launch_bounds__(512, 6) void k_phase2m(
    float* __restrict__ m_g, float* __restrict__ x_g, unsigned short* __restrict__ xjb_g,
    const unsigned short* __restrict__ WBb,
    const float* __restrict__ rib1, const float* __restrict__ rib2,
    const float* __restrict__ db, const float* __restrict__ u,
    const float* __restrict__ rab1, const float* __restrict__ rab2,
    const float* __restrict__ rob1, const float* __restrict__ rob2,
    const float* __restrict__ biN, const float* __restrict__ bjN,
    const unsigned short* __restrict__ outWBb,
    float* __restrict__ Ea, float* __restrict__ Qa,
    float* __restrict__ last2, float* __restrict__ nh, int N){
  __shared__ unsigned short tiles[2][16*136];   // 8704 B
  __shared__ float biasS[16*128];               // 8192 B
  int tid = threadIdx.x, w = tid >> 6, l = tid & 63;
  int m = l & 15, q = l >> 4, rbase = blockIdx.x*16;
  int c = w*16 + m;
  ffrag mC, xC, C;
  float xrow[4];
  int cur = 0;
  const int nst = HASNEXT ? 15 : 13;
  const int slotSeq[15] = {0,1,2,3,4,5,6,7,8,9,10,
                           HASNEXT?13:11, HASNEXT?14:12, 11, 12};
  bfrag Bb[2][4];
  #pragma unroll
  for (int k0 = 0; k0 < 4; ++k0)
    Bb[0][k0] = *(const bfrag*)(WBb + (size_t)slotSeq[0]*16384 + (size_t)((w*4+k0)*64 + l)*8);

  if (tid < 128){
    biasS[0*128+tid]  = rib1[tid];
    biasS[1*128+tid]  = rib1[128+tid];
    biasS[2*128+tid]  = rib1[256+tid];
    biasS[3*128+tid]  = rib2[tid];
    biasS[4*128+tid]  = rib2[128+tid];
    biasS[5*128+tid]  = rib2[256+tid];
    biasS[6*128+tid]  = db[tid];
    biasS[7*128+tid]  = u[tid];
    biasS[8*128+tid]  = rab1[tid];
    biasS[9*128+tid]  = rab1[128+tid];
    biasS[10*128+tid] = rab2[tid];
    biasS[11*128+tid] = rab2[128+tid];
    biasS[12*128+tid] = rob1[tid];
    biasS[13*128+tid] = rob2[tid];
    biasS[14*128+tid] = biN[tid];
    biasS[15*128+tid] = bjN[tid];
  }
  // S0: load m -> mC; tiles[0] = act(m); preload x rows (used at stage 6)
  #pragma unroll
  for (int r = 0; r < 4; ++r){
    int row = rbase + q*4 + r;
    xrow[r] = x_g[(size_t)row*128 + c];
    float v = m_g[(size_t)row*128 + c];
    mC[r] = v;
    tiles[0][(q*4+r)*136 + c] = f2b(actf(v));
  }
  #pragma unroll 2
  for (int s = 0; s < nst; ++s){
    __syncthreads();
    if (s+1 < nst){
      #pragma unroll
      for (int k0 = 0; k0 < 4; ++k0)
        Bb[(s+1)&1][k0] = *(const bfrag*)(WBb + (size_t)slotSeq[s+1]*16384 + (size_t)((w*4+k0)*64 + l)*8);
    }
    {
      const unsigned short* tp = &tiles[cur][0];
      ffrag cc = {0.f,0.f,0.f,0.f};
      #pragma unroll
      for (int k0 = 0; k0 < 4; ++k0){
        bfrag A = *(const bfrag*)(tp + m*136 + k0*32 + q*8);
        cc = __builtin_amdgcn_mfma_f32_16x16x32_bf16(A, Bb[s&1][k0], cc, 0, 0, 0);
      }
      C = cc;
    }
    if (HASNEXT && s == 11){            // WiN -> m_g for next block
      float bb = biasS[14*128 + c];
      #pragma unroll
      for (int r = 0; r < 4; ++r)
        m_g[(size_t)(rbase + q*4 + r)*128 + c] = actf(C[r] + bb);
    } else if (HASNEXT && s == 12){     // WjN -> xjb (bf16) for next block
      float bb = biasS[15*128 + c];
      #pragma unroll
      for (int r = 0; r < 4; ++r)
        xjb_g[(size_t)(rbase + q*4 + r)*128 + c] = f2b(actf(C[r] + bb));
    } else if (s == 6){                 // x-update
      float uu = biasS[7*128 + c], bb = biasS[6*128 + c];
      #pragma unroll
      for (int r = 0; r < 4; ++r){
        float nv = uu*xrow[r] + C[r] + bb;
        xC[r] = nv;
        tiles[1-cur][(q*4+r)*136 + c] = f2b(actf(nv));
      }
      cur ^= 1;
    } else if (s == 1 || s == 3 || s == 5){   // m-residual close
      float bb = biasS[(3 + (s>>1))*128 + c];
      #pragma unroll
      for (int r = 0; r < 4; ++r){
        float nv = mC[r] + C[r] + bb;
        mC[r] = nv;
        tiles[1-cur][(q*4+r)*136 + c] = f2b(actf(nv));
      }
      cur ^= 1;
    } else if (s == 8 || s == 10){            // x-residual close
      float bb = biasS[(10 + ((s-8)>>1))*128 + c];
      #pragma unroll
      for (int r = 0; r < 4; ++r){
        float nv = xC[r] + C[r] + bb;
        xC[r] = nv;
        tiles[1-cur][(q*4+r)*136 + c] = f2b(actf(nv));
        if (HASNEXT && s == 10)
          x_g[(size_t)(rbase + q*4 + r)*128 + c] = nv;
      }
      cur ^= 1;
    } else if ((HASNEXT && s == 14) || (!HASNEXT && s == 12)){  // o = x + h@roW2 + b
      float bb = biasS[13*128 + c];
      #pragma unroll
      for (int r = 0; r < 4; ++r){
        float ov = xC[r] + C[r] + bb;
        tiles[1-cur][(q*4+r)*136 + c] = f2b(actf(ov));
      }
      cur ^= 1;
    } else {                                  // act-only stages
      int bidx = (s==0)?0:(s==2)?1:(s==4)?2:(s==7)?8:(s==9)?9:12;
      float bb = biasS[bidx*128 + c];
      #pragma unroll
      for (int r = 0; r < 4; ++r)
        tiles[1-cur][(q*4+r)*136 + c] = f2b(actf(C[r] + bb));
      cur ^= 1;
    }
  }
  // head: out = act(o) @ outW (padded to 16 cols), wave 0 only
  __syncthreads();
  if (w == 0){
    const unsigned short* tp = &tiles[cur][0];
    bfrag A[4];
    #pragma unroll
    for (int k0 = 0; k0 < 4; ++k0)
      A[k0] = *(const bfrag*)(tp + m*136 + k0*32 + q*8);
    ffrag Ch = {0.f,0.f,0.f,0.f};
    #pragma unroll
    for (int k0 = 0; k0 < 4; ++k0){
      bfrag B = *(const bfrag*)(outWBb + (size_t)(k0*64 + l)*8);
      Ch = __builtin_amdgcn_mfma_f32_16x16x32_bf16(A[k0], B, Ch, 0, 0, 0);
    }
    int col = m;
    if (col < 2){
      float tpa = 0.f;
      #pragma unroll
      for (int r = 0; r < 4; ++r){
        int row = rbase + q*4 + r;
        float val = Ch[r];
        if (NH){
          if (col == 0) Ea[row] += val; else Qa[row] += val;
        } else {
          if (col == 0) Ea[row]  = val; else Qa[row]  = val;
        }
        float sq = val*val;
        if (NH){
          float lastv = last2[row*2 + col];
          tpa += sq/(sq + lastv + 1e-7f);
        }
        last2[row*2 + col] = sq;
      }
      if (NH) unsafeAtomicAdd(nh, tpa);
    }
  }
}

__global__ __launch_bounds__(256) void k_final(
    const int* __restrict__ Z, const float* __restrict__ Ea, const float* __restrict__ Qa,
    const float* __restrict__ Es, const float* __restrict__ Eh,
    const float* __restrict__ Qs, const float* __restrict__ Qh,
    const float* __restrict__ nh, float* __restrict__ out, int N, int P){
  int n = blockIdx.x*256 + threadIdx.x;
  if (n < N){
    int z = Z[n];
    out[n]   = Es[z]*Ea[n] + Eh[z];
    out[N+n] = Qs[z]*Qa[n] + Qh[z];
  }
  if (blockIdx.x == 0 && threadIdx.x == 0)
    out[(size_t)2*N + P] = nh[0] / (2.f * (float)N);
}

extern "C" void kernel_launch(void* const* d_in, const int* in_sizes, int n_in,
                              void* d_out, int out_size, void* d_ws, size_t ws_size,
                              hipStream_t stream){
  const int N = in_sizes[0];
  const int P = in_sizes[2];
  const int F = 128;

  const int* Z      = (const int*)d_in[0];
  const float* R    = (const float*)d_in[1];
  const int* idx_i  = (const int*)d_in[2];
  const int* idx_j  = (const int*)d_in[3];
  const float* emb  = (const float*)d_in[4];
  const float* cent = (const float*)d_in[5];
  const float* wid  = (const float*)d_in[6];
  const float* k2f  = (const float*)d_in[7];
  const float* Wi   = (const float*)d_in[8];  const float* bi   = (const float*)d_in[9];
  const float* Wj   = (const float*)d_in[10]; const float* bj   = (const float*)d_in[11];
  const float* riW1 = (const float*)d_in[12]; const float* rib1 = (const float*)d_in[13];
  const float* riW2 = (const float*)d_in[14]; const float* rib2 = (const float*)d_in[15];
  const float* dWp  = (const float*)d_in[16]; const float* dbp  = (const float*)d_in[17];
  const float* u    = (const float*)d_in[18];
  const float* raW1 = (const float*)d_in[19]; const float* rab1 = (const float*)d_in[20];
  const float* raW2 = (const float*)d_in[21]; const float* rab2 = (const float*)d_in[22];
  const float* roW1 = (const float*)d_in[23]; const float* rob1 = (const float*)d_in[24];
  const float* roW2 = (const float*)d_in[25]; const float* rob2 = (const float*)d_in[26];
  const float* outW = (const float*)d_in[27];
  const float* Es   = (const float*)d_in[28]; const float* Eh   = (const float*)d_in[29];
  const float* Qs   = (const float*)d_in[30]; const float* Qh   = (const float*)d_in[31];

  char* ws = (char*)d_ws;
  size_t off = 0;
  float* DijF  = (float*)(ws + off); off += (size_t)P*4;
  float* D_s   = (float*)(ws + off); off += (size_t)P*4;
  int*   i_s   = (int*)  (ws + off); off += (size_t)P*4;
  int*   j_s   = (int*)  (ws + off); off += (size_t)P*4;
  unsigned short* rbf_s = (unsigned short*)(ws + off); off += (size_t)P*64*2;
  unsigned short* k2fP  = (unsigned short*)(ws + off); off += (size_t)5*16*64*8*2;
  unsigned short* WBall = (unsigned short*)(ws + off); off += (size_t)75*16384*2;
  unsigned short* outWB = (unsigned short*)(ws + off); off += (size_t)5*2048*2;
  float* x     = (float*)(ws + off); off += (size_t)N*F*4;
  unsigned short* xjb = (unsigned short*)(ws + off); off += (size_t)N*F*2;
  float* m     = (float*)(ws + off); off += (size_t)N*F*4;
  float* last2 = (float*)(ws + off); off += (size_t)N*2*4;
  float* Ea    = (float*)(ws + off); off += (size_t)N*4;
  float* Qa    = (float*)(ws + off); off += (size_t)N*4;
  float* nh    = (float*)(ws + off); off += 256;          // zero region start (nh)
  int*   counts= (int*)  (ws + off); off += (size_t)N*4;  // zero region end
  int*   cursor= (int*)  (ws + off); off += (size_t)N*4;

  float* outF = (float*)d_out;
  float* Dout = outF + (size_t)2*N;

  const int nzero = N + 64;
  k_zero<<<dim3((nzero+255)/256), dim3(256), 0, stream>>>(nh, nzero);
  k_dij_count<<<dim3((P+255)/256), dim3(256), 0, stream>>>(R, idx_i, idx_j, DijF, Dout, counts, P);
  k_scan<<<dim3(1), dim3(1024), 0, stream>>>(counts, cursor, N);
  k_scatter<<<dim3((P+255)/256), dim3(256), 0, stream>>>(idx_i, idx_j, DijF, cursor, i_s, j_s, D_s, P);
  const int prep2n = P*8 + 75*2048 + 5120 + 1280;
  k_prep2<<<dim3((prep2n+255)/256), dim3(256), 0, stream>>>(
      D_s, cent, wid, rbf_s,
      riW1, riW2, dWp, raW1, raW2, roW1, roW2, Wi, Wj, k2f, outW,
      WBall, k2fP, outWB, P);

  const int G16 = (N + 15)/16;
  k_phase1m<<<dim3(G16), dim3(128), 0, stream>>>(Z, emb, WBall + (size_t)4*15*16384,
                                                 bi, bj, x, m, xjb, N);

  const int pmg = (P + 255)/256;   // 64 pairs/wave, 4 waves/block
  for (int b = 0; b < 5; ++b){
    k_pairmsg2<<<dim3(pmg), dim3(256), 0, stream>>>(rbf_s, k2fP + (size_t)b*16*64*8,
                                                    i_s, j_s, xjb, m, P);
    const unsigned short* WBb = WBall + (size_t)b*15*16384;
    const float* a_rib1 = rib1 + (size_t)b*3*F;
    const float* a_rib2 = rib2 + (size_t)b*3*F;
    const float* a_db   = dbp  + (size_t)b*F;
    const float* a_u    = u    + (size_t)b*F;
    const float* a_rab1 = rab1 + (size_t)b*2*F;
    const float* a_rab2 = rab2 + (size_t)b*2*F;
    const float* a_rob1 = rob1 + (size_t)b*F;
    const float* a_rob2 = rob2 + (size_t)b*F;
    int bn = (b < 4) ? (b+1) : 0;
    const float* a_biN = bi + (size_t)bn*F;
    const float* a_bjN = bj + (size_t)bn*F;
    const unsigned short* oWB = outWB + (size_t)b*2048;
    if (b == 0){
      k_phase2m<1,0><<<dim3(G16), dim3(512), 0, stream>>>(m, x, xjb, WBb,
        a_rib1, a_rib2, a_db, a_u, a_rab1, a_rab2, a_rob1, a_rob2,
        a_biN, a_bjN, oWB, Ea, Qa, last2, nh, N);
    } else if (b < 4){
      k_phase2m<1,1><<<dim3(G16), dim3(512), 0, stream>>>(m, x, xjb, WBb,
        a_rib1, a_rib2, a_db, a_u, a_rab1, a_rab2, a_rob1, a_rob2,
        a_biN, a_bjN, oWB, Ea, Qa, last2, nh, N);
    } else {
      k_phase2m<0,1><<<dim3(G16), dim3(512), 0, stream>>>(m, x, xjb, WBb,
        a_rib1, a_rib2, a_db, a_u, a_rab1, a_rab2, a_rob1, a_rob2,
        a_biN, a_bjN, oWB, Ea, Qa, last2, nh, N);
    }
  }
  k_final<<<dim3((N+255)/256), dim3(256), 0, stream>>>(Z, Ea, Qa, Es, Eh, Qs, Qh, nh, outF, N, P);
}

// Round 15
// 423.682 us; speedup vs baseline: 1.1794x; 1.0429x over previous
//
#include <hip/hip_runtime.h>

typedef __attribute__((ext_vector_type(8))) short bfrag;   // 8 bf16 (4 VGPRs)
typedef __attribute__((ext_vector_type(4))) float ffrag;   // 4 fp32

__device__ __forceinline__ unsigned short f2b(float f){
  unsigned int u = __float_as_uint(f);
  return (unsigned short)((u + 0x7FFFu + ((u >> 16) & 1u)) >> 16);
}
__device__ __forceinline__ float b2f_lo(unsigned int v){   // low ushort -> float
  return __uint_as_float(v << 16);
}
__device__ __forceinline__ float b2f_hi(unsigned int v){   // high ushort -> float
  return __uint_as_float(v & 0xFFFF0000u);
}
__device__ __forceinline__ int rfl(int v){ return __builtin_amdgcn_readfirstlane(v); }
// shifted softplus via v_exp/v_log (both base-2 on gfx950)
__device__ __forceinline__ float actf(float v){
  float e = __builtin_amdgcn_exp2f(-fabsf(v)*1.44269504088896341f);
  return fmaxf(v, 0.f) + __builtin_amdgcn_logf(1.f + e)*0.69314718055994531f - 0.69314718055994531f;
}

// ---------- small utility kernels ----------
__global__ __launch_bounds__(256) void k_zero(float* p, int n){
  int i = blockIdx.x*256 + threadIdx.x;
  if (i < n) p[i] = 0.f;
}

__global__ __launch_bounds__(256) void k_dij_count(
    const float* __restrict__ R, const int* __restrict__ idx_i, const int* __restrict__ idx_j,
    float* __restrict__ DijF, float* __restrict__ Dout, int* __restrict__ counts, int P){
  int p = blockIdx.x*256 + threadIdx.x;
  if (p >= P) return;
  int i = idx_i[p], j = idx_j[p];
  float dx = R[i*3+0] - R[j*3+0];
  float dy = R[i*3+1] - R[j*3+1];
  float dz = R[i*3+2] - R[j*3+2];
  float D = sqrtf(fmaxf(dx*dx + dy*dy + dz*dz, 0.f));
  DijF[p] = D;
  Dout[p] = D;
  atomicAdd(&counts[i], 1);
}

// single-kernel exclusive scan of counts -> cursor
__global__ __launch_bounds__(1024) void k_scan(const int* __restrict__ counts,
    int* __restrict__ cursor, int N){
  __shared__ int wsum[16];
  int tid = threadIdx.x;
  int CH = (N + 1023) >> 10;
  int base = tid * CH;
  int s = 0;
  for (int i = 0; i < CH; ++i){
    int idx = base + i;
    s += (idx < N) ? counts[idx] : 0;
  }
  int lane = tid & 63, w = tid >> 6;
  int v = s;
  #pragma unroll
  for (int off = 1; off < 64; off <<= 1){
    int t = __shfl_up(v, off, 64);
    if (lane >= off) v += t;
  }
  if (lane == 63) wsum[w] = v;
  __syncthreads();
  if (tid < 16){
    int t = wsum[tid];
    int vv = t;
    #pragma unroll
    for (int off = 1; off < 16; off <<= 1){
      int u = __shfl_up(vv, off, 64);
      if (tid >= off) vv += u;
    }
    wsum[tid] = vv - t;   // exclusive wave offset
  }
  __syncthreads();
  int run = (v - s) + wsum[w];
  for (int i = 0; i < CH; ++i){
    int idx = base + i;
    if (idx < N){ cursor[idx] = run; run += counts[idx]; }
  }
}

__global__ __launch_bounds__(256) void k_scatter(const int* __restrict__ idx_i,
    const int* __restrict__ idx_j, const float* __restrict__ DijF,
    int* __restrict__ cursor, int* __restrict__ i_s, int* __restrict__ j_s,
    float* __restrict__ D_s, int P){
  int p = blockIdx.x*256 + threadIdx.x;
  if (p >= P) return;
  int i = idx_i[p];
  int pos = atomicAdd(&cursor[i], 1);
  i_s[pos] = i;
  j_s[pos] = idx_j[p];
  D_s[pos] = DijF[p];
}

// MERGED: rbf expansion (gid < P*8) + all weight repacks (gid >= P*8).
__global__ __launch_bounds__(256) void k_prep2(
    const float* __restrict__ D_s, const float* __restrict__ cent, const float* __restrict__ wid,
    unsigned short* __restrict__ rbf_s,
    const float* __restrict__ riW1, const float* __restrict__ riW2,
    const float* __restrict__ dW,   const float* __restrict__ raW1,
    const float* __restrict__ raW2, const float* __restrict__ roW1,
    const float* __restrict__ roW2, const float* __restrict__ Wi,
    const float* __restrict__ Wj,   const float* __restrict__ k2f,
    const float* __restrict__ outW,
    unsigned short* __restrict__ WBall, unsigned short* __restrict__ k2fP,
    unsigned short* __restrict__ outWB, int P){
  int gid0 = blockIdx.x*256 + threadIdx.x;
  if (gid0 < P*8){
    int t = gid0 >> 3, kg = gid0 & 7;
    float D = D_s[t];
    float xc = D * 0.1f;
    float cut = 0.f;
    if (xc < 1.f){
      float x3 = xc*xc*xc, x4 = x3*xc, x5 = x4*xc;
      cut = 1.f - 6.f*x5 + 15.f*x4 - 10.f*x3;
    }
    float eD = __builtin_amdgcn_exp2f(-D*1.44269504088896341f);
    bfrag o;
    #pragma unroll
    for (int i = 0; i < 8; ++i){
      int k = kg*8 + i;
      float tt = eD - cent[k];
      float v = cut * __builtin_amdgcn_exp2f(-wid[k]*tt*tt*1.44269504088896341f);
      o[i] = (short)f2b(v);
    }
    *(bfrag*)(rbf_s + (size_t)gid0*8) = o;
    return;
  }
  int gid = gid0 - P*8;
  if (gid < 75*2048){
    int i = gid >> 11, r = gid & 2047;
    const float* S;
    int slot;
    if (i < 15)      { S = riW1 + (size_t)i*16384;      slot = (i/3)*15 + 2*(i%3); }
    else if (i < 30) { int j=i-15; S = riW2 + (size_t)j*16384; slot = (j/3)*15 + 2*(j%3) + 1; }
    else if (i < 35) { int j=i-30; S = dW   + (size_t)j*16384; slot = j*15 + 6; }
    else if (i < 45) { int j=i-35; S = raW1 + (size_t)j*16384; slot = (j/2)*15 + 7 + 2*(j%2); }
    else if (i < 55) { int j=i-45; S = raW2 + (size_t)j*16384; slot = (j/2)*15 + 8 + 2*(j%2); }
    else if (i < 60) { int j=i-55; S = roW1 + (size_t)j*16384; slot = j*15 + 11; }
    else if (i < 65) { int j=i-60; S = roW2 + (size_t)j*16384; slot = j*15 + 12; }
    else if (i < 70) { int j=i-65; S = Wi   + (size_t)j*16384; slot = ((j==0)?4:(j-1))*15 + 13; }
    else             { int j=i-70; S = Wj   + (size_t)j*16384; slot = ((j==0)?4:(j-1))*15 + 14; }
    int fr = r >> 6, l = r & 63;
    int T = fr >> 2, k0 = fr & 3;
    int n = T*16 + (l & 15);
    int kbase = k0*32 + (l >> 4)*8;
    unsigned short* D = WBall + ((size_t)slot*2048 + r)*8;
    ushort4 o0, o1;
    o0.x=f2b(S[(kbase+0)*128+n]); o0.y=f2b(S[(kbase+1)*128+n]);
    o0.z=f2b(S[(kbase+2)*128+n]); o0.w=f2b(S[(kbase+3)*128+n]);
    o1.x=f2b(S[(kbase+4)*128+n]); o1.y=f2b(S[(kbase+5)*128+n]);
    o1.z=f2b(S[(kbase+6)*128+n]); o1.w=f2b(S[(kbase+7)*128+n]);
    ((ushort4*)D)[0]=o0; ((ushort4*)D)[1]=o1;
  } else if (gid < 75*2048 + 5120){
    int g = gid - 75*2048;
    int l = g & 63, fr = (g >> 6) & 15, b = g >> 10;
    int tile = fr >> 1, kh = fr & 1;
    const float* src = k2f + (size_t)b*64*128;
    int n = tile*16 + (l & 15);
    int kbase = kh*32 + (l >> 4)*8;
    ushort4 o0, o1;
    o0.x = f2b(src[(kbase+0)*128+n]); o0.y = f2b(src[(kbase+1)*128+n]);
    o0.z = f2b(src[(kbase+2)*128+n]); o0.w = f2b(src[(kbase+3)*128+n]);
    o1.x = f2b(src[(kbase+4)*128+n]); o1.y = f2b(src[(kbase+5)*128+n]);
    o1.z = f2b(src[(kbase+6)*128+n]); o1.w = f2b(src[(kbase+7)*128+n]);
    ushort4* dst = (ushort4*)(k2fP + (size_t)g*8);
    dst[0] = o0; dst[1] = o1;
  } else if (gid < 75*2048 + 5120 + 1280){
    int g = gid - (75*2048 + 5120);
    int b = g >> 8, r = g & 255;
    int l = r & 63;
    int col = l & 15;
    int k0 = r >> 6;
    int kbase = k0*32 + (l >> 4)*8;
    ushort4 o0 = {0,0,0,0}, o1 = {0,0,0,0};
    if (col < 2){
      const float* S = outW + (size_t)b*256;
      o0.x=f2b(S[(kbase+0)*2+col]); o0.y=f2b(S[(kbase+1)*2+col]);
      o0.z=f2b(S[(kbase+2)*2+col]); o0.w=f2b(S[(kbase+3)*2+col]);
      o1.x=f2b(S[(kbase+4)*2+col]); o1.y=f2b(S[(kbase+5)*2+col]);
      o1.z=f2b(S[(kbase+6)*2+col]); o1.w=f2b(S[(kbase+7)*2+col]);
    }
    unsigned short* D = outWB + ((size_t)b*256 + r)*8;
    ((ushort4*)D)[0]=o0; ((ushort4*)D)[1]=o1;
  }
}

// ---------- MFMA tile machinery ----------
__device__ __forceinline__ void mmtile(const unsigned short* tile,
    const unsigned short* __restrict__ WB, int w, int l, ffrag C[4]){
  int m = l & 15, q = l >> 4;
  bfrag A[4];
  #pragma unroll
  for (int k0 = 0; k0 < 4; ++k0)
    A[k0] = *(const bfrag*)(tile + m*136 + k0*32 + q*8);
  #pragma unroll
  for (int tt = 0; tt < 4; ++tt){
    ffrag c = {0.f,0.f,0.f,0.f};
    const bfrag* bp = (const bfrag*)(WB + (((w*4+tt)*4)*64 + l)*8);
    #pragma unroll
    for (int k0 = 0; k0 < 4; ++k0)
      c = __builtin_amdgcn_mfma_f32_16x16x32_bf16(A[k0], bp[k0*64], c, 0, 0, 0);
    C[tt] = c;
  }
}

// phase1: x = emb[Z]; m_g = act(act(x)@Wi0+bi0); xjb = act(act(x)@Wj0+bj0) [bf16]
__global__ __launch_bounds__(128) void k_phase1m(
    const int* __restrict__ Z, const float* __restrict__ emb,
    const unsigned short* __restrict__ WB45,
    const float* __restrict__ bi0, const float* __restrict__ bj0,
    float* __restrict__ x_g, float* __restrict__ m_g, unsigned short* __restrict__ xjb_g, int N){
  __shared__ unsigned short tile[16*136];
  int tid = threadIdx.x, w = tid >> 6, l = tid & 63;
  int m = l & 15, q = l >> 4, rbase = blockIdx.x*16;
  #pragma unroll
  for (int r = 0; r < 4; ++r){
    int row = rbase + q*4 + r;
    int z = Z[row];
    #pragma unroll
    for (int tt = 0; tt < 4; ++tt){
      int c = (w*4+tt)*16 + m;
      float v = emb[(size_t)z*128 + c];
      x_g[(size_t)row*128 + c] = v;
      tile[(q*4+r)*136 + c] = f2b(actf(v));
    }
  }
  __syncthreads();
  ffrag C[4];
  mmtile(tile, WB45 + 13*16384, w, l, C);
  #pragma unroll
  for (int tt = 0; tt < 4; ++tt){
    int c = (w*4+tt)*16 + m;
    float bb = bi0[c];
    #pragma unroll
    for (int r = 0; r < 4; ++r)
      m_g[(size_t)(rbase + q*4 + r)*128 + c] = actf(C[tt][r] + bb);
  }
  mmtile(tile, WB45 + 14*16384, w, l, C);
  #pragma unroll
  for (int tt = 0; tt < 4; ++tt){
    int c = (w*4+tt)*16 + m;
    float bb = bj0[c];
    #pragma unroll
    for (int r = 0; r < 4; ++r)
      xjb_g[(size_t)(rbase + q*4 + r)*128 + c] = f2b(actf(C[tt][r] + bb));
  }
}

// ---------- pair-message: R8/R11 register-lean version, 4 blocks/CU ----------
// MEASURED-BEST form (4 alternatives tried and reverted): same-batch gather
// issue before MFMA, full B[16] resident, SGPR indices via readfirstlane,
// no software double-buffer. ~35us/dispatch, gather-latency-bound.
__global__ __launch_bounds__(256, 4) void k_pairmsg2(
    const unsigned short* __restrict__ rbf_s, const unsigned short* __restrict__ k2fP,
    const int* __restrict__ i_s, const int* __restrict__ j_s,
    const unsigned short* __restrict__ xj, float* __restrict__ m_g, int P){
  __shared__ float G[4][16*130];
  int tid = threadIdx.x, w = tid >> 6, l = tid & 63;
  float* Gw = &G[w][0];
  bfrag B[16];
  #pragma unroll
  for (int t = 0; t < 16; ++t)
    B[t] = *(const bfrag*)(k2fP + (size_t)(t*64 + l)*8);
  int wstart = (blockIdx.x*4 + w)*64;
  if (wstart >= P) return;
  int row16 = l & 15, quad = l >> 4;
  float a0 = 0.f, a1 = 0.f;
  int iCur = -1;
  #pragma unroll 1
  for (int bi2 = 0; bi2 < 4; ++bi2){
    int bt = wstart + bi2*16;
    // A-frags: sequential rbf_s stream
    bfrag A0 = *(const bfrag*)(rbf_s + (size_t)(bt + row16)*64 + quad*8);
    bfrag A1 = *(const bfrag*)(rbf_s + (size_t)(bt + row16)*64 + 32 + quad*8);
    // wave-uniform indices -> SGPRs
    int ip[16], jp[16];
    #pragma unroll
    for (int g = 0; g < 4; ++g){
      int4 it = *(const int4*)(i_s + bt + g*4);
      int4 jt = *(const int4*)(j_s + bt + g*4);
      ip[g*4+0]=rfl(it.x); ip[g*4+1]=rfl(it.y); ip[g*4+2]=rfl(it.z); ip[g*4+3]=rfl(it.w);
      jp[g*4+0]=rfl(jt.x); jp[g*4+1]=rfl(jt.y); jp[g*4+2]=rfl(jt.z); jp[g*4+3]=rfl(jt.w);
    }
    // issue gathers BEFORE the MFMA block (latency hides under MFMA + G-writes)
    unsigned int xv[16];
    #pragma unroll
    for (int k = 0; k < 16; ++k)
      xv[k] = *(const unsigned int*)(xj + (size_t)jp[k]*128 + 2*l);
    #pragma unroll
    for (int t = 0; t < 8; ++t){
      ffrag C = {0.f,0.f,0.f,0.f};
      C = __builtin_amdgcn_mfma_f32_16x16x32_bf16(A0, B[t*2],   C, 0, 0, 0);
      C = __builtin_amdgcn_mfma_f32_16x16x32_bf16(A1, B[t*2+1], C, 0, 0, 0);
      #pragma unroll
      for (int r = 0; r < 4; ++r)
        Gw[(quad*4+r)*130 + t*16 + row16] = C[r];
    }
    #pragma unroll
    for (int k = 0; k < 16; ++k){
      int i = ip[k];
      if (i != iCur){
        if (iCur >= 0){
          unsafeAtomicAdd(&m_g[(size_t)iCur*128 + 2*l],     a0);
          unsafeAtomicAdd(&m_g[(size_t)iCur*128 + 2*l + 1], a1);
        }
        iCur = i; a0 = 0.f; a1 = 0.f;
      }
      float g0 = Gw[k*130 + 2*l], g1 = Gw[k*130 + 2*l + 1];
      a0 = fmaf(g0, b2f_lo(xv[k]), a0);
      a1 = fmaf(g1, b2f_hi(xv[k]), a1);
    }
  }
  if (iCur >= 0){
    unsafeAtomicAdd(&m_g[(size_t)iCur*128 + 2*l],     a0);
    unsafeAtomicAdd(&m_g[(size_t)iCur*128 + 2*l + 1], a1);
  }
}

// ---------- phase 2: 16 rows/block, 8 waves, 1 col-tile/wave (measured-best) ----------
// 625 blocks, 3 blocks/CU (16.9KB LDS, (512,6) cap) -> 24 waves/CU: deep TLP
// for the 15-stage barrier-separated chain. N % 16 == 0 -> no row guards.
template<int HASNEXT, int NH>
__global__ __launch_bounds__(512, 6) void k_phase2m(
    float* __restrict__ m_g, float* __restrict__ x_g, unsigned short* __restrict__ xjb_g,
    const unsigned short* __restrict__ WBb,
    const float* __restrict__ rib1, const float* __restrict__ rib2,
    const float* __restrict__ db, const float* __restrict__ u,
    const float* __restrict__ rab1, const float* __restrict__ rab2,
    const float* __restrict__ rob1, const float* __restrict__ rob2,
    const float* __restrict__ biN, const float* __restrict__ bjN,
    const unsigned short* __restrict__ outWBb,
    float* __restrict__ Ea, float* __restrict__ Qa,
    float* __restrict__ last2, float* __restrict__ nh, int N){
  __shared__ unsigned short tiles[2][16*136];   // 8704 B
  __shared__ float biasS[16*128];               // 8192 B
  int tid = threadIdx.x, w = tid >> 6, l = tid & 63;
  int m = l & 15, q = l >> 4, rbase = blockIdx.x*16;
  int c = w*16 + m;
  ffrag mC, xC, C;
  float xrow[4];
  int cur = 0;
  const int nst = HASNEXT ? 15 : 13;
  const int slotSeq[15] = {0,1,2,3,4,5,6,7,8,9,10,
                           HASNEXT?13:11, HASNEXT?14:12, 11, 12};
  bfrag Bb[2][4];
  #pragma unroll
  for (int k0 = 0; k0 < 4; ++k0)
    Bb[0][k0] = *(const bfrag*)(WBb + (size_t)slotSeq[0]*16384 + (size_t)((w*4+k0)*64 + l)*8);

  if (tid < 128){
    biasS[0*128+tid]  = rib1[tid];
    biasS[1*128+tid]  = rib1[128+tid];
    biasS[2*128+tid]  = rib1[256+tid];
    biasS[3*128+tid]  = rib2[tid];
    biasS[4*128+tid]  = rib2[128+tid];
    biasS[5*128+tid]  = rib2[256+tid];
    biasS[6*128+tid]  = db[tid];
    biasS[7*128+tid]  = u[tid];
    biasS[8*128+tid]  = rab1[tid];
    biasS[9*128+tid]  = rab1[128+tid];
    biasS[10*128+tid] = rab2[tid];
    biasS[11*128+tid] = rab2[128+tid];
    biasS[12*128+tid] = rob1[tid];
    biasS[13*128+tid] = rob2[tid];
    biasS[14*128+tid] = biN[tid];
    biasS[15*128+tid] = bjN[tid];
  }
  // S0: load m -> mC; tiles[0] = act(m); preload x rows (used at stage 6)
  #pragma unroll
  for (int r = 0; r < 4; ++r){
    int row = rbase + q*4 + r;
    xrow[r] = x_g[(size_t)row*128 + c];
    float v = m_g[(size_t)row*128 + c];
    mC[r] = v;
    tiles[0][(q*4+r)*136 + c] = f2b(actf(v));
  }
  #pragma unroll 2
  for (int s = 0; s < nst; ++s){
    __syncthreads();
    if (s+1 < nst){
      #pragma unroll
      for (int k0 = 0; k0 < 4; ++k0)
        Bb[(s+1)&1][k0] = *(const bfrag*)(WBb + (size_t)slotSeq[s+1]*16384 + (size_t)((w*4+k0)*64 + l)*8);
    }
    {
      const unsigned short* tp = &tiles[cur][0];
      ffrag cc = {0.f,0.f,0.f,0.f};
      #pragma unroll
      for (int k0 = 0; k0 < 4; ++k0){
        bfrag A = *(const bfrag*)(tp + m*136 + k0*32 + q*8);
        cc = __builtin_amdgcn_mfma_f32_16x16x32_bf16(A, Bb[s&1][k0], cc, 0, 0, 0);
      }
      C = cc;
    }
    if (HASNEXT && s == 11){            // WiN -> m_g for next block
      float bb = biasS[14*128 + c];
      #pragma unroll
      for (int r = 0; r < 4; ++r)
        m_g[(size_t)(rbase + q*4 + r)*128 + c] = actf(C[r] + bb);
    } else if (HASNEXT && s == 12){     // WjN -> xjb (bf16) for next block
      float bb = biasS[15*128 + c];
      #pragma unroll
      for (int r = 0; r < 4; ++r)
        xjb_g[(size_t)(rbase + q*4 + r)*128 + c] = f2b(actf(C[r] + bb));
    } else if (s == 6){                 // x-update
      float uu = biasS[7*128 + c], bb = biasS[6*128 + c];
      #pragma unroll
      for (int r = 0; r < 4; ++r){
        float nv = uu*xrow[r] + C[r] + bb;
        xC[r] = nv;
        tiles[1-cur][(q*4+r)*136 + c] = f2b(actf(nv));
      }
      cur ^= 1;
    } else if (s == 1 || s == 3 || s == 5){   // m-residual close
      float bb = biasS[(3 + (s>>1))*128 + c];
      #pragma unroll
      for (int r = 0; r < 4; ++r){
        float nv = mC[r] + C[r] + bb;
        mC[r] = nv;
        tiles[1-cur][(q*4+r)*136 + c] = f2b(actf(nv));
      }
      cur ^= 1;
    } else if (s == 8 || s == 10){            // x-residual close
      float bb = biasS[(10 + ((s-8)>>1))*128 + c];
      #pragma unroll
      for (int r = 0; r < 4; ++r){
        float nv = xC[r] + C[r] + bb;
        xC[r] = nv;
        tiles[1-cur][(q*4+r)*136 + c] = f2b(actf(nv));
        if (HASNEXT && s == 10)
          x_g[(size_t)(rbase + q*4 + r)*128 + c] = nv;
      }
      cur ^= 1;
    } else if ((HASNEXT && s == 14) || (!HASNEXT && s == 12)){  // o = x + h@roW2 + b
      float bb = biasS[13*128 + c];
      #pragma unroll
      for (int r = 0; r < 4; ++r){
        float ov = xC[r] + C[r] + bb;
        tiles[1-cur][(q*4+r)*136 + c] = f2b(actf(ov));
      }
      cur ^= 1;
    } else {                                  // act-only stages
      int bidx = (s==0)?0:(s==2)?1:(s==4)?2:(s==7)?8:(s==9)?9:12;
      float bb = biasS[bidx*128 + c];
      #pragma unroll
      for (int r = 0; r < 4; ++r)
        tiles[1-cur][(q*4+r)*136 + c] = f2b(actf(C[r] + bb));
      cur ^= 1;
    }
  }
  // head: out = act(o) @ outW (padded to 16 cols), wave 0 only
  __syncthreads();
  if (w == 0){
    const unsigned short* tp = &tiles[cur][0];
    bfrag A[4];
    #pragma unroll
    for (int k0 = 0; k0 < 4; ++k0)
      A[k0] = *(const bfrag*)(tp + m*136 + k0*32 + q*8);
    ffrag Ch = {0.f,0.f,0.f,0.f};
    #pragma unroll
    for (int k0 = 0; k0 < 4; ++k0){
      bfrag B = *(const bfrag*)(outWBb + (size_t)(k0*64 + l)*8);
      Ch = __builtin_amdgcn_mfma_f32_16x16x32_bf16(A[k0], B, Ch, 0, 0, 0);
    }
    int col = m;
    if (col < 2){
      float tpa = 0.f;
      #pragma unroll
      for (int r = 0; r < 4; ++r){
        int row = rbase + q*4 + r;
        float val = Ch[r];
        if (NH){
          if (col == 0) Ea[row] += val; else Qa[row] += val;
        } else {
          if (col == 0) Ea[row]  = val; else Qa[row]  = val;
        }
        float sq = val*val;
        if (NH){
          float lastv = last2[row*2 + col];
          tpa += sq/(sq + lastv + 1e-7f);
        }
        last2[row*2 + col] = sq;
      }
      if (NH) unsafeAtomicAdd(nh, tpa);
    }
  }
}

__global__ __launch_bounds__(256) void k_final(
    const int* __restrict__ Z, const float* __restrict__ Ea, const float* __restrict__ Qa,
    const float* __restrict__ Es, const float* __restrict__ Eh,
    const float* __restrict__ Qs, const float* __restrict__ Qh,
    const float* __restrict__ nh, float* __restrict__ out, int N, int P){
  int n = blockIdx.x*256 + threadIdx.x;
  if (n < N){
    int z = Z[n];
    out[n]   = Es[z]*Ea[n] + Eh[z];
    out[N+n] = Qs[z]*Qa[n] + Qh[z];
  }
  if (blockIdx.x == 0 && threadIdx.x == 0)
    out[(size_t)2*N + P] = nh[0] / (2.f * (float)N);
}

extern "C" void kernel_launch(void* const* d_in, const int* in_sizes, int n_in,
                              void* d_out, int out_size, void* d_ws, size_t ws_size,
                              hipStream_t stream){
  const int N = in_sizes[0];
  const int P = in_sizes[2];
  const int F = 128;

  const int* Z      = (const int*)d_in[0];
  const float* R    = (const float*)d_in[1];
  const int* idx_i  = (const int*)d_in[2];
  const int* idx_j  = (const int*)d_in[3];
  const float* emb  = (const float*)d_in[4];
  const float* cent = (const float*)d_in[5];
  const float* wid  = (const float*)d_in[6];
  const float* k2f  = (const float*)d_in[7];
  const float* Wi   = (const float*)d_in[8];  const float* bi   = (const float*)d_in[9];
  const float* Wj   = (const float*)d_in[10]; const float* bj   = (const float*)d_in[11];
  const float* riW1 = (const float*)d_in[12]; const float* rib1 = (const float*)d_in[13];
  const float* riW2 = (const float*)d_in[14]; const float* rib2 = (const float*)d_in[15];
  const float* dWp  = (const float*)d_in[16]; const float* dbp  = (const float*)d_in[17];
  const float* u    = (const float*)d_in[18];
  const float* raW1 = (const float*)d_in[19]; const float* rab1 = (const float*)d_in[20];
  const float* raW2 = (const float*)d_in[21]; const float* rab2 = (const float*)d_in[22];
  const float* roW1 = (const float*)d_in[23]; const float* rob1 = (const float*)d_in[24];
  const float* roW2 = (const float*)d_in[25]; const float* rob2 = (const float*)d_in[26];
  const float* outW = (const float*)d_in[27];
  const float* Es   = (const float*)d_in[28]; const float* Eh   = (const float*)d_in[29];
  const float* Qs   = (const float*)d_in[30]; const float* Qh   = (const float*)d_in[31];

  char* ws = (char*)d_ws;
  size_t off = 0;
  float* DijF  = (float*)(ws + off); off += (size_t)P*4;
  float* D_s   = (float*)(ws + off); off += (size_t)P*4;
  int*   i_s   = (int*)  (ws + off); off += (size_t)P*4;
  int*   j_s   = (int*)  (ws + off); off += (size_t)P*4;
  unsigned short* rbf_s = (unsigned short*)(ws + off); off += (size_t)P*64*2;
  unsigned short* k2fP  = (unsigned short*)(ws + off); off += (size_t)5*16*64*8*2;
  unsigned short* WBall = (unsigned short*)(ws + off); off += (size_t)75*16384*2;
  unsigned short* outWB = (unsigned short*)(ws + off); off += (size_t)5*2048*2;
  float* x     = (float*)(ws + off); off += (size_t)N*F*4;
  unsigned short* xjb = (unsigned short*)(ws + off); off += (size_t)N*F*2;
  float* m     = (float*)(ws + off); off += (size_t)N*F*4;
  float* last2 = (float*)(ws + off); off += (size_t)N*2*4;
  float* Ea    = (float*)(ws + off); off += (size_t)N*4;
  float* Qa    = (float*)(ws + off); off += (size_t)N*4;
  float* nh    = (float*)(ws + off); off += 256;          // zero region start (nh)
  int*   counts= (int*)  (ws + off); off += (size_t)N*4;  // zero region end
  int*   cursor= (int*)  (ws + off); off += (size_t)N*4;

  float* outF = (float*)d_out;
  float* Dout = outF + (size_t)2*N;

  const int nzero = N + 64;
  k_zero<<<dim3((nzero+255)/256), dim3(256), 0, stream>>>(nh, nzero);
  k_dij_count<<<dim3((P+255)/256), dim3(256), 0, stream>>>(R, idx_i, idx_j, DijF, Dout, counts, P);
  k_scan<<<dim3(1), dim3(1024), 0, stream>>>(counts, cursor, N);
  k_scatter<<<dim3((P+255)/256), dim3(256), 0, stream>>>(idx_i, idx_j, DijF, cursor, i_s, j_s, D_s, P);
  const int prep2n = P*8 + 75*2048 + 5120 + 1280;
  k_prep2<<<dim3((prep2n+255)/256), dim3(256), 0, stream>>>(
      D_s, cent, wid, rbf_s,
      riW1, riW2, dWp, raW1, raW2, roW1, roW2, Wi, Wj, k2f, outW,
      WBall, k2fP, outWB, P);

  const int G16 = (N + 15)/16;
  k_phase1m<<<dim3(G16), dim3(128), 0, stream>>>(Z, emb, WBall + (size_t)4*15*16384,
                                                 bi, bj, x, m, xjb, N);

  const int pmg = (P + 255)/256;   // 64 pairs/wave, 4 waves/block
  for (int b = 0; b < 5; ++b){
    k_pairmsg2<<<dim3(pmg), dim3(256), 0, stream>>>(rbf_s, k2fP + (size_t)b*16*64*8,
                                                    i_s, j_s, xjb, m, P);
    const unsigned short* WBb = WBall + (size_t)b*15*16384;
    const float* a_rib1 = rib1 + (size_t)b*3*F;
    const float* a_rib2 = rib2 + (size_t)b*3*F;
    const float* a_db   = dbp  + (size_t)b*F;
    const float* a_u    = u    + (size_t)b*F;
    const float* a_rab1 = rab1 + (size_t)b*2*F;
    const float* a_rab2 = rab2 + (size_t)b*2*F;
    const float* a_rob1 = rob1 + (size_t)b*F;
    const float* a_rob2 = rob2 + (size_t)b*F;
    int bn = (b < 4) ? (b+1) : 0;
    const float* a_biN = bi + (size_t)bn*F;
    const float* a_bjN = bj + (size_t)bn*F;
    const unsigned short* oWB = outWB + (size_t)b*2048;
    if (b == 0){
      k_phase2m<1,0><<<dim3(G16), dim3(512), 0, stream>>>(m, x, xjb, WBb,
        a_rib1, a_rib2, a_db, a_u, a_rab1, a_rab2, a_rob1, a_rob2,
        a_biN, a_bjN, oWB, Ea, Qa, last2, nh, N);
    } else if (b < 4){
      k_phase2m<1,1><<<dim3(G16), dim3(512), 0, stream>>>(m, x, xjb, WBb,
        a_rib1, a_rib2, a_db, a_u, a_rab1, a_rab2, a_rob1, a_rob2,
        a_biN, a_bjN, oWB, Ea, Qa, last2, nh, N);
    } else {
      k_phase2m<0,1><<<dim3(G16), dim3(512), 0, stream>>>(m, x, xjb, WBb,
        a_rib1, a_rib2, a_db, a_u, a_rab1, a_rab2, a_rob1, a_rob2,
        a_biN, a_bjN, oWB, Ea, Qa, last2, nh, N);
    }
  }
  k_final<<<dim3((N+255)/256), dim3(256), 0, stream>>>(Z, Ea, Qa, Es, Eh, Qs, Qh, nh, outF, N, P);
}